// Round 1
// 4990.761 us; speedup vs baseline: 1.4744x; 1.4744x over previous
//
#include <hip/hip_runtime.h>
#include <stdint.h>

// LoraLSTM on MI355X. FP32 I/O, bf16 internal pipeline.
//  - fold LoRA into frozen weights: W_eff = W + 2*(BL@A) -> bf16
//  - per layer, per time-chunk of CL steps:
//      gemm<AF32>: gx = in @ W_ih_eff^T + bias (bf16 gx)
//      rec<OUTF32>: CL LSTM steps; 16 wgs/dir own 32 hidden units; W_hh in regs.
//  - R7 change vs R6: tagged-packet h exchange (single round trip).
//    Each u64 packet = [step_tag:32 | h1:bf16 | h0:bf16]. Writers issue 2
//    relaxed agent-scope b64 stores right after the cell math -- NO ack
//    barrier, NO flag array, NO spin-then-load. Readers poll the 32 packets
//    they stage (8192 distinct lines, no hot flag lines); the detecting load
//    IS the data load. Double-parity buffers kept (overwrite of parity p with
//    tag s+2 only after polling ALL s+1 packets, which data-depend on the
//    writers having consumed every s packet -> safe without flags).
//    Also: 3 barriers/step (was 4), fast sigmoid/tanh via v_exp+v_rcp.

typedef unsigned short u16;
typedef unsigned long long u64;
typedef __bf16 bf16x8 __attribute__((ext_vector_type(8)));
typedef float f32x4 __attribute__((ext_vector_type(4)));

#define NCELL 4
#define HID 512
#define INP 1024
#define G4 2048
#define BATCH 32
#define SEQ 512
#define RLORA 8
#define NW 16   // workgroups per direction in recurrence
#define HPW 32  // HID / NW
#define HTAGN 8192  // tagged u64 packets (2 h each) per dir per parity (= 32*512/2)

__device__ __forceinline__ float bf2f(u16 u) {
  union { uint32_t i; float f; } v;
  v.i = ((uint32_t)u) << 16;
  return v.f;
}
__device__ __forceinline__ u16 f2bf(float f) {
  union { float f; uint32_t i; } v;
  v.f = f;
  uint32_t lsb = (v.i >> 16) & 1;
  return (u16)((v.i + 0x7fffu + lsb) >> 16);
}
__device__ __forceinline__ float sigm(float x) {
  return __builtin_amdgcn_rcpf(1.f + __expf(-x));
}
__device__ __forceinline__ float ftanh(float x) {
  // 1 - 2/(e^{2x}+1); robust at +/-inf (rcp(inf)=0)
  return 1.f - 2.f * __builtin_amdgcn_rcpf(__expf(2.f * x) + 1.f);
}

// ---------------- weight folding: W_eff = W + 2 * BL @ A  (fp32 in, bf16 out) ---------
template <int K>
__global__ void fold_kernel(const float* __restrict__ w, const float* __restrict__ a,
                            const float* __restrict__ bl, u16* __restrict__ weff) {
  int64_t idx = (int64_t)blockIdx.x * blockDim.x + threadIdx.x;
  if (idx >= (int64_t)NCELL * G4 * K) return;
  int d = (int)(idx % K);
  int64_t gc = idx / K;
  int cell = (int)(gc / G4);
  float acc = w[idx];
#pragma unroll
  for (int r = 0; r < RLORA; ++r)
    acc += 2.0f * bl[gc * RLORA + r] * a[(int64_t)cell * RLORA * K + r * K + d];
  weff[idx] = f2bf(acc);
}

__global__ void bias_kernel(const float* __restrict__ b_ih, const float* __restrict__ b_hh,
                            float* __restrict__ bias) {
  int i = blockIdx.x * blockDim.x + threadIdx.x;
  if (i < NCELL * G4) bias[i] = b_ih[i] + b_hh[i];
}

// ---------------- gx chunk GEMM ----------------
template <bool AF32>
__global__ __launch_bounds__(256) void gemm_kernel(const void* __restrict__ Ain,
                                                   const u16* __restrict__ W,
                                                   const float* __restrict__ bias,
                                                   u16* __restrict__ gx, int tw0, int tw1,
                                                   int CL) {
  __shared__ alignas(16) u16 As[128][72];
  __shared__ alignas(16) u16 Bs[128][72];
  const int tid = threadIdx.x;
  const int dir = blockIdx.z;
  const int m0 = blockIdx.x * 128;
  const int n0 = blockIdx.y * 128;
  const int tw = dir ? tw1 : tw0;
  const int Mc = BATCH * CL;
  const u16* Wc = W + (int64_t)dir * G4 * INP;
  const float* bc = bias + dir * G4;
  u16* gxc = gx + (int64_t)dir * Mc * G4;
  const int wave = tid >> 6, lane = tid & 63;
  const int wm = wave & 1, wn = wave >> 1;
  const int llo = lane & 15, lhi = lane >> 4;

  int64_t aoff[4];
  const u16* bptr[4];
  int srow[4], ssc[4];
#pragma unroll
  for (int i = 0; i < 4; ++i) {
    int s = i * 256 + tid;
    srow[i] = s >> 3;
    ssc[i] = s & 7;
    int lr = m0 + srow[i];
    int b = lr / CL;
    int tt = tw + (lr - b * CL);
    aoff[i] = ((int64_t)b * SEQ + tt) * INP + ssc[i] * 8;
    bptr[i] = Wc + (int64_t)(n0 + srow[i]) * INP + ssc[i] * 8;
  }

  const f32x4 fzero = {0.f, 0.f, 0.f, 0.f};
  f32x4 acc[4][4];
#pragma unroll
  for (int i = 0; i < 4; ++i)
#pragma unroll
    for (int j = 0; j < 4; ++j) acc[i][j] = fzero;

  for (int kt = 0; kt < INP / 64; ++kt) {
    const int kb = kt * 64;
    __syncthreads();
#pragma unroll
    for (int i = 0; i < 4; ++i) {
      if (AF32) {
        const float* src = (const float*)Ain + aoff[i] + kb;
        uint32_t p[4];
#pragma unroll
        for (int q = 0; q < 4; ++q)
          p[q] = (uint32_t)f2bf(src[2 * q]) | ((uint32_t)f2bf(src[2 * q + 1]) << 16);
        *(uint4*)&As[srow[i]][ssc[i] * 8] = make_uint4(p[0], p[1], p[2], p[3]);
      } else {
        *(uint4*)&As[srow[i]][ssc[i] * 8] = *(const uint4*)((const u16*)Ain + aoff[i] + kb);
      }
      *(uint4*)&Bs[srow[i]][ssc[i] * 8] = *(const uint4*)(bptr[i] + kb);
    }
    __syncthreads();
#pragma unroll
    for (int ks = 0; ks < 2; ++ks) {
      bf16x8 af[4], bfr[4];
#pragma unroll
      for (int i = 0; i < 4; ++i) {
        af[i] = *(const bf16x8*)&As[wm * 64 + i * 16 + llo][ks * 32 + lhi * 8];
        bfr[i] = *(const bf16x8*)&Bs[wn * 64 + i * 16 + llo][ks * 32 + lhi * 8];
      }
#pragma unroll
      for (int i = 0; i < 4; ++i)
#pragma unroll
        for (int j = 0; j < 4; ++j)
          acc[i][j] = __builtin_amdgcn_mfma_f32_16x16x32_bf16(af[i], bfr[j], acc[i][j], 0, 0, 0);
    }
  }
#pragma unroll
  for (int i = 0; i < 4; ++i) {
    const int lr0 = m0 + wm * 64 + i * 16 + lhi * 4;
#pragma unroll
    for (int j = 0; j < 4; ++j) {
      const int ncol = n0 + wn * 64 + j * 16 + llo;
      const float bv = bc[ncol];
#pragma unroll
      for (int r = 0; r < 4; ++r) gxc[(int64_t)(lr0 + r) * G4 + ncol] = f2bf(acc[i][j][r] + bv);
    }
  }
}

// ---------------- recurrence chunk ----------------
template <bool OUTF32>
__global__ __launch_bounds__(256, 1) void rec_kernel(
    const u16* __restrict__ gx,    // [2][B*CL][G4] bf16 (chunk-local)
    const u16* __restrict__ Whh,   // [2][G4][HID] bf16
    u64* __restrict__ htag,        // [2 dirs][2 par][HTAGN] tagged packets
    void* __restrict__ outp,
    float* __restrict__ hn, float* __restrict__ cn,  // fp32, in d_out
    float* __restrict__ cstate,    // [4 cells][B][H] fp32 (ws)
    int cell_base, int s0, int CL) {
  const int tid = threadIdx.x;
  const int dir = blockIdx.x / NW;
  const int wg = blockIdx.x % NW;
  const int hb = wg * HPW;
  const int wave = tid >> 6, lane = tid & 63;
  const int llo = lane & 15, lhi = lane >> 4;
  const int Mc = BATCH * CL;

  const u16* gxc = gx + (int64_t)dir * Mc * G4;
  const u16* Wc = Whh + (int64_t)dir * G4 * HID;
  u64* ht_dir = htag + (int64_t)dir * (2 * HTAGN);
  float* cst = cstate + (int64_t)(cell_base + dir) * BATCH * HID;

  __shared__ alignas(16) u16 h_lds[2 * 16 * 64 * 8];  // fragment order, 32KB
  __shared__ float g_lds[4][BATCH][HPW + 1];

  // W_hh fragments for this wave's gate, held for the whole chunk.
  uint4 wfrag[2][16];
#pragma unroll
  for (int j = 0; j < 2; ++j)
#pragma unroll
    for (int ks = 0; ks < 16; ++ks) {
      const int col = wave * HID + hb + j * 16 + llo;
      wfrag[j][ks] = *(const uint4*)(Wc + (int64_t)col * HID + ks * 32 + lhi * 8);
    }
  if (s0 == 0) {
    for (int i = tid; i < 2 * 16 * 64 * 8 / 2; i += 256) ((uint32_t*)h_lds)[i] = 0;
  }
  // c state in registers (thread-private: this thread owns (b, hb+j0..j0+3) forever)
  const int cb = tid >> 3, j0 = (tid & 7) * 4;
  float creg[4];
#pragma unroll
  for (int u = 0; u < 4; ++u) creg[u] = (s0 == 0) ? 0.f : cst[cb * HID + hb + j0 + u];
  // writer's fragment address (ks = wg for this block's columns)
  const int wmt = cb >> 4, wllo = cb & 15, wlhi = j0 >> 3, wjof = j0 & 7;
  const int64_t wfragidx = ((int64_t)((wmt * 16 + wg) * 64 + wlhi * 16 + wllo) * 8 + wjof) >> 2;
  u64* const wpkt_base = ht_dir + 2 * wfragidx;  // + parity*HTAGN

  for (int s = s0; s < s0 + CL; ++s) {
    const int ls = s - s0;
    const int t = dir ? (SEQ - 1 - s) : s;
    const int lcol = dir ? (CL - 1 - ls) : ls;
    // gx tile -> acc (loads issued before the poll; they drain during it)
    f32x4 acc[2][2];
#pragma unroll
    for (int mt = 0; mt < 2; ++mt)
#pragma unroll
      for (int j = 0; j < 2; ++j) {
        const int col = wave * HID + hb + j * 16 + llo;
#pragma unroll
        for (int r = 0; r < 4; ++r) {
          const int b = mt * 16 + lhi * 4 + r;
          acc[mt][j][r] = bf2f(gxc[(int64_t)(b * CL + lcol) * G4 + col]);
        }
      }
    if (s > 0) {
      // tagged poll: the detecting load IS the data load (single round trip)
      u64* src = ht_dir + ((s - 1) & 1) * HTAGN;
      const uint32_t want = (uint32_t)s;
      u64 va[16], vb[16];
#pragma unroll
      for (int k = 0; k < 16; ++k) {
        const int idx = tid + k * 256;
        va[k] = __hip_atomic_load(src + 2 * idx, __ATOMIC_RELAXED, __HIP_MEMORY_SCOPE_AGENT);
        vb[k] = __hip_atomic_load(src + 2 * idx + 1, __ATOMIC_RELAXED, __HIP_MEMORY_SCOPE_AGENT);
      }
      for (;;) {
        uint32_t bad = 0;
#pragma unroll
        for (int k = 0; k < 16; ++k) {
          bad |= ((uint32_t)(va[k] >> 32)) ^ want;
          bad |= ((uint32_t)(vb[k] >> 32)) ^ want;
        }
        if (bad == 0) break;
#pragma unroll
        for (int k = 0; k < 16; ++k) {
          const int idx = tid + k * 256;
          if ((uint32_t)(va[k] >> 32) != want)
            va[k] = __hip_atomic_load(src + 2 * idx, __ATOMIC_RELAXED, __HIP_MEMORY_SCOPE_AGENT);
          if ((uint32_t)(vb[k] >> 32) != want)
            vb[k] =
                __hip_atomic_load(src + 2 * idx + 1, __ATOMIC_RELAXED, __HIP_MEMORY_SCOPE_AGENT);
        }
      }
      __syncthreads();  // prev step's LDS readers done before overwrite
      u64* dst = (u64*)h_lds;
#pragma unroll
      for (int k = 0; k < 16; ++k) {
        const int idx = tid + k * 256;
        dst[idx] = ((u64)(uint32_t)vb[k] << 32) | (uint32_t)va[k];
      }
    }
    __syncthreads();  // staged h visible to all waves
#pragma unroll
    for (int ks = 0; ks < 16; ++ks) {
      bf16x8 af[2];
#pragma unroll
      for (int mt = 0; mt < 2; ++mt)
        af[mt] = *(const bf16x8*)&h_lds[((mt * 16 + ks) * 64 + lane) * 8];
#pragma unroll
      for (int mt = 0; mt < 2; ++mt)
#pragma unroll
        for (int j = 0; j < 2; ++j)
          acc[mt][j] = __builtin_amdgcn_mfma_f32_16x16x32_bf16(
              af[mt], __builtin_bit_cast(bf16x8, wfrag[j][ks]), acc[mt][j], 0, 0, 0);
    }
    // cross-wave gate exchange
#pragma unroll
    for (int mt = 0; mt < 2; ++mt)
#pragma unroll
      for (int j = 0; j < 2; ++j)
#pragma unroll
        for (int r = 0; r < 4; ++r)
          g_lds[wave][mt * 16 + lhi * 4 + r][j * 16 + llo] = acc[mt][j][r];
    __syncthreads();
    float hv[4], cv[4];
    u16 h16[4];
#pragma unroll
    for (int u = 0; u < 4; ++u) {
      const int jj = j0 + u;
      const float gi = g_lds[0][cb][jj], gf = g_lds[1][cb][jj];
      const float gg = g_lds[2][cb][jj], go = g_lds[3][cb][jj];
      float c = creg[u];
      c = sigm(gf) * c + sigm(gi) * ftanh(gg);
      hv[u] = sigm(go) * ftanh(c);
      cv[u] = c;
      creg[u] = c;
      h16[u] = f2bf(hv[u]);
    }
    {  // tagged h packets: data + step tag in one u64, relaxed agent stores.
      const u64 tg = ((u64)(uint32_t)(s + 1)) << 32;
      const u64 lo = (u64)((uint32_t)h16[0] | ((uint32_t)h16[1] << 16));
      const u64 hi = (u64)((uint32_t)h16[2] | ((uint32_t)h16[3] << 16));
      u64* hw = wpkt_base + (s & 1) * HTAGN;
      __hip_atomic_store(hw, tg | lo, __ATOMIC_RELAXED, __HIP_MEMORY_SCOPE_AGENT);
      __hip_atomic_store(hw + 1, tg | hi, __ATOMIC_RELAXED, __HIP_MEMORY_SCOPE_AGENT);
    }
    // non-critical stores off the exchange path
    {
      const int64_t obase = ((int64_t)cb * SEQ + t) * (2 * HID) + dir * HID + hb + j0;
      if (OUTF32) {
        *(float4*)((float*)outp + obase) = make_float4(hv[0], hv[1], hv[2], hv[3]);
      } else {
        uint32_t* ow = (uint32_t*)((u16*)outp + obase);
        ow[0] = (uint32_t)h16[0] | ((uint32_t)h16[1] << 16);
        ow[1] = (uint32_t)h16[2] | ((uint32_t)h16[3] << 16);
      }
      if (s == SEQ - 1) {
        const int cg = cell_base + dir;
        const int64_t nbase = ((int64_t)cg * BATCH + cb) * HID + hb + j0;
        *(float4*)(hn + nbase) = make_float4(hv[0], hv[1], hv[2], hv[3]);
        *(float4*)(cn + nbase) = make_float4(cv[0], cv[1], cv[2], cv[3]);
      }
    }
  }
  // persist c for next chunk
#pragma unroll
  for (int u = 0; u < 4; ++u) cst[cb * HID + hb + j0 + u] = creg[u];
}

extern "C" void kernel_launch(void* const* d_in, const int* in_sizes, int n_in, void* d_out,
                              int out_size, void* d_ws, size_t ws_size, hipStream_t stream) {
  const float* x = (const float*)d_in[0];
  const float* w_ih = (const float*)d_in[1];
  const float* w_hh = (const float*)d_in[2];
  const float* b_ih = (const float*)d_in[3];
  const float* b_hh = (const float*)d_in[4];
  const float* a_ih = (const float*)d_in[5];
  const float* bl_ih = (const float*)d_in[6];
  const float* a_hh = (const float*)d_in[7];
  const float* bl_hh = (const float*)d_in[8];
  float* out = (float*)d_out;  // fp32 outputs

  char* ws = (char*)d_ws;
  const size_t O_WIH = 0;                                        // 16,777,216
  const size_t O_WHH = O_WIH + (size_t)NCELL * G4 * INP * 2;     // + 8,388,608
  const size_t O_BIAS = O_WHH + (size_t)NCELL * G4 * HID * 2;    // + 32,768
  const size_t O_CST = O_BIAS + (size_t)NCELL * G4 * 4;          // + 262,144
  const size_t O_HBUF = O_CST + (size_t)NCELL * BATCH * HID * 4; // + 262,144
  const size_t O_MID = O_HBUF + (size_t)NCELL * 2 * HTAGN * 8;   // + 524,288
  const size_t O_GX = O_MID + (size_t)BATCH * SEQ * 2 * HID * 2; // + 33,554,432
  u16* w_ih_eff = (u16*)(ws + O_WIH);
  u16* w_hh_eff = (u16*)(ws + O_WHH);
  float* bias = (float*)(ws + O_BIAS);
  float* cstate = (float*)(ws + O_CST);
  u64* hbuf = (u64*)(ws + O_HBUF);
  u16* mid = (u16*)(ws + O_MID);
  u16* gxb = (u16*)(ws + O_GX);

  int CL = 128;
  while (CL > 8 && O_GX + (size_t)2 * BATCH * CL * G4 * 2 > ws_size) CL >>= 1;
  const int nch = SEQ / CL;

  // zero all step tags once per run (tags are monotone within a run; this
  // prevents stale tags from a previous bench iteration matching)
  (void)hipMemsetAsync(ws + O_HBUF, 0, (size_t)NCELL * 2 * HTAGN * 8, stream);

  {
    int64_t tot = (int64_t)NCELL * G4 * INP;
    fold_kernel<INP><<<(int)((tot + 255) / 256), 256, 0, stream>>>(w_ih, a_ih, bl_ih, w_ih_eff);
  }
  {
    int64_t tot = (int64_t)NCELL * G4 * HID;
    fold_kernel<HID><<<(int)((tot + 255) / 256), 256, 0, stream>>>(w_hh, a_hh, bl_hh, w_hh_eff);
  }
  bias_kernel<<<(NCELL * G4 + 255) / 256, 256, 0, stream>>>(b_ih, b_hh, bias);

  float* hn = out + (size_t)BATCH * SEQ * (2 * HID);
  float* cn = hn + (size_t)NCELL * BATCH * HID;

  dim3 gemm_grid(BATCH * CL / 128, G4 / 128, 2);
  for (int layer = 0; layer < 2; ++layer) {
    const u16* wih = w_ih_eff + (size_t)layer * 2 * G4 * INP;
    const u16* whh = w_hh_eff + (size_t)layer * 2 * G4 * HID;
    const float* bi = bias + (size_t)layer * 2 * G4;
    u64* hbL = hbuf + (size_t)layer * 4 * HTAGN;
    for (int ci = 0; ci < nch; ++ci) {
      const int tw0 = ci * CL;
      const int tw1 = SEQ - (ci + 1) * CL;
      if (layer == 0) {
        gemm_kernel<true><<<gemm_grid, 256, 0, stream>>>(x, wih, bi, gxb, tw0, tw1, CL);
        rec_kernel<false><<<2 * NW, 256, 0, stream>>>(gxb, whh, hbL, mid, hn, cn, cstate,
                                                      0, ci * CL, CL);
      } else {
        gemm_kernel<false><<<gemm_grid, 256, 0, stream>>>(mid, wih, bi, gxb, tw0, tw1, CL);
        rec_kernel<true><<<2 * NW, 256, 0, stream>>>(gxb, whh, hbL, out, hn, cn, cstate,
                                                     2, ci * CL, CL);
      }
    }
  }
}